// Round 18
// baseline (285.547 us; speedup 1.0000x reference)
//
#include <hip/hip_runtime.h>
#include <hip/hip_bf16.h>

// ---------------- problem dims ----------------
#define NT  512      // tokens
#define NH  2048     // hidden
#define NE  8        // experts
#define NI  1408     // expert intermediate
#define NIS 5632     // shared intermediate

typedef __bf16 bf16x8 __attribute__((ext_vector_type(8)));
typedef float  f32x4  __attribute__((ext_vector_type(4)));

// async global->LDS DMA, 16B per lane, wave-uniform LDS base + lane*16
#define GLDS(gp, lp) __builtin_amdgcn_global_load_lds( \
    (const __attribute__((address_space(1))) void*)(gp), \
    (__attribute__((address_space(3))) void*)(lp), 16, 0, 0)

// ---------------- workspace layout (bytes) ----------------
static constexpr size_t WS_XBF  = 0;                                  // 512*2048 bf16
static constexpr size_t WS_SEL  = WS_XBF + (size_t)NT*NH*2;           // 1024 int
static constexpr size_t WS_WTS  = WS_SEL + 4096;
static constexpr size_t WS_CNT  = WS_WTS + 4096;
static constexpr size_t WS_OFFE = WS_CNT + 32;
static constexpr size_t WS_TOK  = WS_OFFE + 32;
static constexpr size_t WS_PWT  = WS_TOK + 4096;
static constexpr size_t WS_SLOT = WS_PWT + 4096;
static constexpr size_t WS_G    = WS_SLOT + 4096;                     // 1024*1408 bf16
static constexpr size_t WS_U    = WS_G   + (size_t)1024*NI*2;
static constexpr size_t WS_HBF  = WS_U   + (size_t)1024*NI*2;         // 1024*1408 bf16
static constexpr size_t WS_PAIR = WS_HBF + (size_t)1024*NI*2;         // 1024*2048 bf16
static constexpr size_t WS_SHG  = WS_PAIR+ (size_t)1024*NH*2;         // 512*5632 bf16
static constexpr size_t WS_SHU  = WS_SHG + (size_t)NT*NIS*2;
static constexpr size_t WS_SHBF = WS_SHU + (size_t)NT*NIS*2;          // 512*5632 bf16
static constexpr size_t WS_SHP  = WS_SHBF+ (size_t)NT*NIS*2;          // 2*512*2048 bf16

// ---------------- router: one wave per token ----------------
__global__ void router_kernel(const float* __restrict__ x, const float* __restrict__ gw,
                              float* __restrict__ out_logits,
                              int* __restrict__ sel, float* __restrict__ wts)
{
    int w    = threadIdx.x >> 6;
    int lane = threadIdx.x & 63;
    int t    = blockIdx.x * 4 + w;
    int e    = lane & 7, c = lane >> 3;
    const float* xr = x  + (size_t)t * NH + c * 256;
    const float* gr = gw + (size_t)e * NH + c * 256;
    float acc = 0.f;
    #pragma unroll 8
    for (int it = 0; it < 64; ++it) {
        float4 xv = *(const float4*)(xr + it*4);
        float4 gv = *(const float4*)(gr + it*4);
        acc += xv.x*gv.x + xv.y*gv.y + xv.z*gv.z + xv.w*gv.w;
    }
    acc += __shfl_xor(acc, 8);
    acc += __shfl_xor(acc, 16);
    acc += __shfl_xor(acc, 32);
    if (lane < 8) out_logits[(size_t)t * NE + e] = acc;

    float l[8];
    #pragma unroll
    for (int j = 0; j < 8; ++j) l[j] = __shfl(acc, j);
    if (lane == 0) {
        int i1 = 0;
        #pragma unroll
        for (int j = 1; j < 8; ++j) if (l[j] > l[i1]) i1 = j;
        int i2 = -1;
        #pragma unroll
        for (int j = 0; j < 8; ++j) {
            if (j == i1) continue;
            if (i2 < 0 || l[j] > l[i2]) i2 = j;
        }
        float d  = expf(l[i2] - l[i1]);
        float w1 = 1.f / (1.f + d);
        float w2 = 1.f - w1;
        sel[2*t]   = i1;  sel[2*t+1] = i2;
        wts[2*t]   = w1;  wts[2*t+1] = w2;
    }
}

// ---------------- wave-parallel deterministic bucketing ----------------
__global__ void bucket_kernel(const int* __restrict__ sel, const float* __restrict__ wts,
                              int* __restrict__ cnt, int* __restrict__ offe,
                              int* __restrict__ tok, float* __restrict__ pwt,
                              int* __restrict__ slot)
{
    int tid  = threadIdx.x;          // 0..511
    int wid  = tid >> 6;             // expert id
    int lane = tid & 63;
    __shared__ int scnt[8], soff[8];

    unsigned long long masks[16];
    int total = 0;
    #pragma unroll
    for (int c = 0; c < 16; ++c) {
        int idx = c * 64 + lane;
        int s = sel[idx];
        unsigned long long m = __ballot(s == wid);
        masks[c] = m;
        total += __popcll(m);
    }
    if (lane == 0) { scnt[wid] = total; cnt[wid] = total; }
    __syncthreads();
    if (tid == 0) {
        int s = 0;
        #pragma unroll
        for (int j = 0; j < 8; ++j) { soff[j] = s; offe[j] = s; s += scnt[j]; }
    }
    __syncthreads();
    int pfx = soff[wid];
    unsigned long long below = (lane == 63) ? ~0ull >> 1 : ((1ull << lane) - 1);
    #pragma unroll
    for (int c = 0; c < 16; ++c) {
        int idx = c * 64 + lane;
        unsigned long long m = masks[c];
        if ((m >> lane) & 1ull) {
            int rank = pfx + (int)__popcll(m & below);
            tok[rank]  = idx >> 1;
            pwt[rank]  = wts[idx];
            slot[idx]  = rank;
        }
        pfx += (int)__popcll(m);
    }
}

// ---------------- fp32 -> bf16 cast (activations) ----------------
__global__ void cast_kernel(const float* __restrict__ src, __bf16* __restrict__ dst, long long n)
{
    long long i = ((long long)blockIdx.x * blockDim.x + threadIdx.x) * 4;
    if (i >= n) return;
    float4 v = *(const float4*)(src + i);
    __bf16 o[4] = { (__bf16)v.x, (__bf16)v.y, (__bf16)v.z, (__bf16)v.w };
    *(uint2*)(dst + i) = *(const uint2*)o;
}

// ---------------- fused silu(g)*u (bf16 in/out) ----------------
__global__ void silu_fused_kernel(const __bf16* __restrict__ g1, const __bf16* __restrict__ u1,
                                  __bf16* __restrict__ h1, long long n1,
                                  const __bf16* __restrict__ g2, const __bf16* __restrict__ u2,
                                  __bf16* __restrict__ h2, long long n2)
{
    long long i = ((long long)blockIdx.x * blockDim.x + threadIdx.x) * 8;
    const __bf16 *g, *u; __bf16* h; long long idx;
    if (i < n1)           { g = g1; u = u1; h = h1; idx = i; }
    else if (i < n1 + n2) { g = g2; u = u2; h = h2; idx = i - n1; }
    else return;
    uint4 gv = *(const uint4*)(g + idx);
    uint4 uv = *(const uint4*)(u + idx);
    const __bf16* gp = (const __bf16*)&gv;
    const __bf16* up = (const __bf16*)&uv;
    __bf16 o[8];
    #pragma unroll
    for (int j = 0; j < 8; ++j) {
        float x = (float)gp[j];
        float y = x / (1.f + __expf(-x)) * (float)up[j];
        o[j] = (__bf16)y;
    }
    *(uint4*)(h + idx) = *(const uint4*)o;
}

// ============ core 128x128 MFMA GEMM — round-14 proven structure ===========
// LDS: As[3][8192] @0 | Bbf[2][8192] @24576 = 40KB.  vmcnt(18) counted.
template<int NK, int LDB, bool GATHER>
__device__ __forceinline__ void gemm_core(char* __restrict__ smem,
    const __bf16* __restrict__ A, int lda,
    const float* __restrict__ B,
    __bf16* __restrict__ C, int ldc,
    int rows, int base, const int* __restrict__ tok, int m0, int n0)
{
    const int tid  = threadIdx.x;
    const int lane = tid & 63;
    const int wid  = tid >> 6;           // 4 waves, 2x2 grid of 64x64
    const int wr   = wid >> 1, wc = wid & 1;

    const int rs0 = (wid*2 + 0)*16 + (lane >> 2);
    const int rs1 = (wid*2 + 1)*16 + (lane >> 2);
    const int cch = lane & 3;
    int ga0 = m0 + rs0, ga1 = m0 + rs1;
    int ar0, ar1;
    if (GATHER) {
        ar0 = tok[base + (ga0 < rows ? ga0 : 0)];
        ar1 = tok[base + (ga1 < rows ? ga1 : 0)];
    } else {
        ar0 = base + (ga0 < rows ? ga0 : 0);
        ar1 = base + (ga1 < rows ? ga1 : 0);
    }
    const __bf16* a0p = A + (size_t)ar0 * lda + (cch ^ (rs0 & 3)) * 8;
    const __bf16* a1p = A + (size_t)ar1 * lda + (cch ^ (rs1 & 3)) * 8;

#define AGLDS(slot, t)                                               \
    {                                                                \
        char* d0 = smem + (slot)*8192 + (wid*2 + 0)*1024;            \
        char* d1 = smem + (slot)*8192 + (wid*2 + 1)*1024;            \
        GLDS(a0p + (size_t)(t)*32, d0);                              \
        GLDS(a1p + (size_t)(t)*32, d1);                              \
    }

    const int cn  = tid & 127;
    const int ckh = tid >> 7;
    const int csw = (cn >> 1) & 3;
    const float* bp = B + (size_t)(ckh * 16) * LDB + n0 + cn;
    char* bbuf0 = smem + 24576;
    char* bbuf1 = smem + 32768;

#define BLOAD(R, t)                                                  \
    {                                                                \
        const float* bq = bp + (size_t)(t) * 32 * LDB;               \
        _Pragma("unroll")                                            \
        for (int j = 0; j < 16; ++j) R[j] = bq[(size_t)j * LDB];     \
    }

#define CONVERT(R, bbase)                                            \
    {                                                                \
        __bf16 ob[16];                                               \
        _Pragma("unroll")                                            \
        for (int j = 0; j < 16; ++j) ob[j] = (__bf16)R[j];           \
        *(uint4*)((bbase) + cn*64 + (((ckh*2 + 0) ^ csw) * 16)) = ((const uint4*)ob)[0]; \
        *(uint4*)((bbase) + cn*64 + (((ckh*2 + 1) ^ csw) * 16)) = ((const uint4*)ob)[1]; \
    }

    const int fr = lane & 15, fq = lane >> 4;
    const int aoff = (wr*64 + fr)*64 + ((fq ^ (fr & 3)) * 16);
    const int boff = (wc*64 + fr)*64 + ((fq ^ ((fr >> 1) & 3)) * 16);

    f32x4 acc[4][4];
    #pragma unroll
    for (int i = 0; i < 4; ++i)
        #pragma unroll
        for (int j = 0; j < 4; ++j) acc[i][j] = f32x4{0.f,0.f,0.f,0.f};

#define MFMAS(slot, bbase)                                           \
    {                                                                \
        const char* Ab = smem + (slot)*8192;                         \
        bf16x8 af[4], bfr[4];                                        \
        _Pragma("unroll")                                            \
        for (int m = 0; m < 4; ++m) af[m]  = *(const bf16x8*)(Ab + aoff + m*1024); \
        _Pragma("unroll")                                            \
        for (int n = 0; n < 4; ++n) bfr[n] = *(const bf16x8*)((bbase) + boff + n*1024); \
        __builtin_amdgcn_s_setprio(1);                               \
        _Pragma("unroll")                                            \
        for (int m = 0; m < 4; ++m)                                  \
            _Pragma("unroll")                                        \
            for (int n = 0; n < 4; ++n)                              \
                acc[m][n] = __builtin_amdgcn_mfma_f32_16x16x32_bf16(af[m], bfr[n], acc[m][n], 0, 0, 0); \
        __builtin_amdgcn_s_setprio(0);                               \
    }

    float b0[16], b1[16];

    BLOAD(b0, 0); AGLDS(0, 0);
    BLOAD(b1, 1); AGLDS(1, 1);
    asm volatile("s_waitcnt vmcnt(18)" ::: "memory");
    CONVERT(b0, bbuf0);
    asm volatile("s_waitcnt lgkmcnt(0)" ::: "memory");
    __builtin_amdgcn_s_barrier();

    int sA = 0, sB = 1, sC = 2;
    #pragma unroll 1
    for (int t = 0; t < NK; t += 2) {
        if (t + 2 < NK) { BLOAD(b0, t + 2); AGLDS(sC, t + 2); }
        __builtin_amdgcn_sched_barrier(0);
        MFMAS(sA, bbuf0);
        __builtin_amdgcn_sched_barrier(0);
        if (t + 2 < NK) asm volatile("s_waitcnt vmcnt(18)" ::: "memory");
        else            asm volatile("s_waitcnt vmcnt(0)" ::: "memory");
        CONVERT(b1, bbuf1);
        asm volatile("s_waitcnt lgkmcnt(0)" ::: "memory");
        __builtin_amdgcn_s_barrier();

        if (t + 3 < NK) { BLOAD(b1, t + 3); AGLDS(sA, t + 3); }
        __builtin_amdgcn_sched_barrier(0);
        MFMAS(sB, bbuf1);
        __builtin_amdgcn_sched_barrier(0);
        if (t + 2 < NK) {
            if (t + 3 < NK) asm volatile("s_waitcnt vmcnt(18)" ::: "memory");
            else            asm volatile("s_waitcnt vmcnt(0)" ::: "memory");
            CONVERT(b0, bbuf0);
        }
        asm volatile("s_waitcnt lgkmcnt(0)" ::: "memory");
        __builtin_amdgcn_s_barrier();

        int tmp = sA; sA = sC; sC = sB; sB = tmp;
    }
#undef AGLDS
#undef BLOAD
#undef CONVERT
#undef MFMAS

    __bf16* ep = (__bf16*)(smem + wid * 9216);   // 64 rows x 72 bf16
    #pragma unroll
    for (int m = 0; m < 4; ++m)
        #pragma unroll
        for (int n = 0; n < 4; ++n)
            #pragma unroll
            for (int q = 0; q < 4; ++q)
                ep[(m*16 + fq*4 + q)*72 + n*16 + fr] = (__bf16)acc[m][n][q];

    const int grow = m0 + wr*64 + lane;
    if (grow < rows) {
        __bf16* cp = C + (size_t)(base + grow) * ldc + n0 + wc*64;
        const __bf16* rp = ep + lane * 72;
        #pragma unroll
        for (int j = 0; j < 8; ++j)
            *(uint4*)(cp + j*8) = *(const uint4*)(rp + j*8);
    }
}

// ============ core 256x128 MFMA GEMM — dual-A-panel (shared tensors) =======
// Same skeleton; 2 A panels (8KB each) per 16KB ring slot; wave (wr,wc)
// computes 128x64 (2 stacked 64x64). Stage = 16 B + 4 A ops -> vmcnt(20).
// LDS: As[3][16384] @0 | Bbf[2][8192] @49152 = 64KB.  NK even.
template<int NK, int LDB>
__device__ __forceinline__ void gemm_core256(char* __restrict__ smem,
    const __bf16* __restrict__ A, int lda,
    const float* __restrict__ B,
    __bf16* __restrict__ C, int ldc,
    int rows, int m0, int n0)
{
    const int tid  = threadIdx.x;
    const int lane = tid & 63;
    const int wid  = tid >> 6;
    const int wr   = wid >> 1, wc = wid & 1;

    // ---- A staging: 4 instrs/wave, instr s covers rows [(wid*4+s)*16, +16)
    const int cch = lane & 3;
    int rsv[4], arv[4];
    #pragma unroll
    for (int s = 0; s < 4; ++s) {
        rsv[s] = (wid*4 + s)*16 + (lane >> 2);
        int ga = m0 + rsv[s];
        arv[s] = (ga < rows ? ga : 0);
    }
    const __bf16* ap0 = A + (size_t)arv[0] * lda + (cch ^ (rsv[0] & 3)) * 8;
    const __bf16* ap1 = A + (size_t)arv[1] * lda + (cch ^ (rsv[1] & 3)) * 8;
    const __bf16* ap2 = A + (size_t)arv[2] * lda + (cch ^ (rsv[2] & 3)) * 8;
    const __bf16* ap3 = A + (size_t)arv[3] * lda + (cch ^ (rsv[3] & 3)) * 8;

#define AGLDS2(slot, t)                                              \
    {                                                                \
        char* db = smem + (slot)*16384 + wid*4096;                   \
        GLDS(ap0 + (size_t)(t)*32, db);                              \
        GLDS(ap1 + (size_t)(t)*32, db + 1024);                       \
        GLDS(ap2 + (size_t)(t)*32, db + 2048);                       \
        GLDS(ap3 + (size_t)(t)*32, db + 3072);                       \
    }

    const int cn  = tid & 127;
    const int ckh = tid >> 7;
    const int csw = (cn >> 1) & 3;
    const float* bp = B + (size_t)(ckh * 16) * LDB + n0 + cn;
    char* bbuf0 = smem + 49152;
    char* bbuf1 = smem + 57344;

#define BLOAD2(R, t)                                                 \
    {                                                                \
        const float* bq = bp + (size_t)(t) * 32 * LDB;               \
        _Pragma("unroll")                                            \
        for (int j = 0; j < 16; ++j) R[j] = bq[(size_t)j * LDB];     \
    }

#define CONVERT2(R, bbase)                                           \
    {                                                                \
        __bf16 ob[16];                                               \
        _Pragma("unroll")                                            \
        for (int j = 0; j < 16; ++j) ob[j] = (__bf16)R[j];           \
        *(uint4*)((bbase) + cn*64 + (((ckh*2 + 0) ^ csw) * 16)) = ((const uint4*)ob)[0]; \
        *(uint4*)((bbase) + cn*64 + (((ckh*2 + 1) ^ csw) * 16)) = ((const uint4*)ob)[1]; \
    }

    const int fr = lane & 15, fq = lane >> 4;
    const int asw = (fq ^ (fr & 3)) * 16;
    const int boff = (wc*64 + fr)*64 + ((fq ^ ((fr >> 1) & 3)) * 16);

    f32x4 acc[2][4][4];
    #pragma unroll
    for (int h = 0; h < 2; ++h)
        #pragma unroll
        for (int i = 0; i < 4; ++i)
            #pragma unroll
            for (int j = 0; j < 4; ++j) acc[h][i][j] = f32x4{0.f,0.f,0.f,0.f};

#define MFMAS2(slot, bbase)                                          \
    {                                                                \
        const char* Ab = smem + (slot)*16384 + wr*8192;              \
        bf16x8 af[8], bfr[4];                                        \
        _Pragma("unroll")                                            \
        for (int h = 0; h < 2; ++h)                                  \
            _Pragma("unroll")                                        \
            for (int m = 0; m < 4; ++m)                              \
                af[h*4+m] = *(const bf16x8*)(Ab + (h*64 + m*16 + fr)*64 + asw); \
        _Pragma("unroll")                                            \
        for (int n = 0; n < 4; ++n) bfr[n] = *(const bf16x8*)((bbase) + boff + n*1024); \
        __builtin_amdgcn_s_setprio(1);                               \
        _Pragma("unroll")                                            \
        for (int h = 0; h < 2; ++h)                                  \
            _Pragma("unroll")                                        \
            for (int m = 0; m < 4; ++m)                              \
                _Pragma("unroll")                                    \
                for (int n = 0; n < 4; ++n)                          \
                    acc[h][m][n] = __builtin_amdgcn_mfma_f32_16x16x32_bf16(af[h*4+m], bfr[n], acc[h][m][n], 0, 0, 0); \
        __builtin_amdgcn_s_setprio(0);                               \
    }

    float b0[16], b1[16];

    BLOAD2(b0, 0); AGLDS2(0, 0);
    BLOAD2(b1, 1); AGLDS2(1, 1);
    asm volatile("s_waitcnt vmcnt(20)" ::: "memory");
    CONVERT2(b0, bbuf0);
    asm volatile("s_waitcnt lgkmcnt(0)" ::: "memory");
    __builtin_amdgcn_s_barrier();

    int sA = 0, sB = 1, sC = 2;
    #pragma unroll 1
    for (int t = 0; t < NK; t += 2) {
        if (t + 2 < NK) { BLOAD2(b0, t + 2); AGLDS2(sC, t + 2); }
        __builtin_amdgcn_sched_barrier(0);
        MFMAS2(sA, bbuf0);
        __builtin_amdgcn_sched_barrier(0);
        if (t + 2 < NK) asm volatile("s_waitcnt vmcnt(20)" ::: "memory");
        else            asm volatile("s_waitcnt vmcnt(0)" ::: "memory");
        CONVERT2(b1, bbuf1);
        asm volatile("s_waitcnt lgkmcnt(0)" ::: "memory");
        __builtin_amdgcn_s_barrier();

        if (t + 3 < NK) { BLOAD2(b1, t + 3); AGLDS2(sA, t + 3); }
        __builtin_amdgcn_sched_barrier(0);
        MFMAS2(sB, bbuf1);
        __builtin_amdgcn_sched_barrier(0);
        if (t + 2 < NK) {
            if (t + 3 < NK) asm volatile("s_waitcnt vmcnt(20)" ::: "memory");
            else            asm volatile("s_waitcnt vmcnt(0)" ::: "memory");
            CONVERT2(b0, bbuf0);
        }
        asm volatile("s_waitcnt lgkmcnt(0)" ::: "memory");
        __builtin_amdgcn_s_barrier();

        int tmp = sA; sA = sC; sC = sB; sB = tmp;
    }
#undef AGLDS2
#undef BLOAD2
#undef CONVERT2
#undef MFMAS2

    // ---- epilogue: two passes (h = 0,1) through per-wave 64x72 region
    __bf16* ep = (__bf16*)(smem + wid * 9216);
    #pragma unroll 1
    for (int h = 0; h < 2; ++h) {
        asm volatile("s_waitcnt lgkmcnt(0)" ::: "memory");  // prev pass reads done
        #pragma unroll
        for (int m = 0; m < 4; ++m)
            #pragma unroll
            for (int n = 0; n < 4; ++n)
                #pragma unroll
                for (int q = 0; q < 4; ++q)
                    ep[(m*16 + fq*4 + q)*72 + n*16 + fr] =
                        (__bf16)((h == 0 ? acc[0] : acc[1])[m][n][q]);
        int grow = m0 + wr*128 + h*64 + lane;
        if (grow < rows) {
            __bf16* cp = C + (size_t)grow * ldc + n0 + wc*64;
            const __bf16* rp = ep + lane * 72;
            #pragma unroll
            for (int j = 0; j < 8; ++j)
                *(uint4*)(cp + j*8) = *(const uint4*)(rp + j*8);
        }
    }
}

// ---------------- phase 1, XCD-local ---------------------------------------
// bid%8 = XCD x; j = bid>>3 in [0,112).
//   j < 88: expert x (BM=128). gu=j/44, r=j%44: n=r%11, m=r/11.
//   j >= 88: shared gate/up (BM=256). s=j-88 in [0,24): z=s/12, rem=s%12:
//            i=rem>>1 -> n=x+8i (guard >=44), m=rem&1 (2 m-tiles of 256).
// Shared B now streamed 2x (was 4x) -> halved demand.
__launch_bounds__(256, 2)
__global__ void gemm_p1(const __bf16* __restrict__ xbf,
                        const float* __restrict__ w_gate, const float* __restrict__ w_up,
                        const float* __restrict__ sh_gate, const float* __restrict__ sh_up,
                        __bf16* __restrict__ gbuf, __bf16* __restrict__ ubuf,
                        __bf16* __restrict__ shg, __bf16* __restrict__ shu,
                        const int* __restrict__ cnt, const int* __restrict__ offe,
                        const int* __restrict__ tok)
{
    __shared__ alignas(16) char smem[65536];
    int g = blockIdx.x;
    int x = g & 7;
    int j = g >> 3;
    if (j < 88) {
        int gu = j / 44;
        int r  = j % 44;
        int n  = r % 11;
        int m  = r / 11;
        int rows = cnt[x], base = offe[x];
        int m0 = m * 128; if (m0 >= rows) return;
        const float* B = (gu == 0 ? w_gate : w_up) + (size_t)x * NH * NI;
        __bf16* C = (gu == 0 ? gbuf : ubuf);
        gemm_core<NH/32, NI, true>(smem, xbf, NH, B, C, NI,
                                   rows, base, tok, m0, n * 128);
    } else {
        int s = j - 88;           // 0..23
        int z = s / 12;
        int rem = s % 12;
        int i = rem >> 1;         // 0..5
        int m = rem & 1;          // 0,1
        int n = x + 8 * i;
        if (n >= 44) return;
        const float* B = (z == 0 ? sh_gate : sh_up);
        __bf16* C = (z == 0 ? shg : shu);
        gemm_core256<NH/32, NIS>(smem, xbf, NH, B, C, NIS,
                                 NT, m * 256, n * 128);
    }
}

// ---------------- phase 3, XCD-local ---------------------------------------
// j = bid>>3 in [0,72).
//   j < 64: expert x down (BM=128, NK=44). n=j%16, m=j/16.
//   j >= 64: shared down (BM=256, split-K x2, NK=88). s=j-64 in [0,8):
//            q=s>>2, rem=s&3: i=rem>>1 -> n=x+8i, m=rem&1.
__launch_bounds__(256, 2)
__global__ void gemm_p3(const __bf16* __restrict__ hbf, const __bf16* __restrict__ shbf,
                        const float* __restrict__ w_down, const float* __restrict__ sh_down,
                        __bf16* __restrict__ pair, __bf16* __restrict__ shp,
                        const int* __restrict__ cnt, const int* __restrict__ offe)
{
    __shared__ alignas(16) char smem[65536];
    int g = blockIdx.x;
    int x = g & 7;
    int j = g >> 3;
    if (j < 64) {
        int n = j % 16;
        int m = j / 16;
        int rows = cnt[x], base = offe[x];
        int m0 = m * 128; if (m0 >= rows) return;
        gemm_core<NI/32, NH, false>(smem, hbf, NI, w_down + (size_t)x * NI * NH,
                                    pair, NH, rows, base, nullptr, m0, n * 128);
    } else {
        int s = j - 64;           // 0..7
        int q = s >> 2;           // K-half 0,1
        int rem = s & 3;
        int i = rem >> 1;         // 0,1
        int m = rem & 1;          // 0,1
        int n = x + 8 * i;        // 0..15
        gemm_core256<NIS/64, NH>(smem, shbf + (size_t)q * (NIS/2), NIS,
                                 sh_down + (size_t)q * (NIS/2) * NH,
                                 shp + (size_t)q * NT * NH, NH,
                                 NT, m * 256, n * 128);
    }
}

// ---------------- final combine (2 shp partials) ---------------------------
__global__ void combine_kernel(const float* __restrict__ x, const float* __restrict__ shexp_w,
                               const __bf16* __restrict__ shp, const __bf16* __restrict__ pair_out,
                               const int* __restrict__ slot, const float* __restrict__ wts,
                               float* __restrict__ out)
{
    int t = blockIdx.x;
    int tid = threadIdx.x;
    const float* xr = x + (size_t)t * NH;

    float p = 0.f;
    #pragma unroll
    for (int j = 0; j < 8; ++j) {
        int k = tid * 8 + j;
        p += xr[k] * shexp_w[k];
    }
    __shared__ float red[256];
    red[tid] = p;
    __syncthreads();
    for (int s = 128; s > 0; s >>= 1) {
        if (tid < s) red[tid] += red[tid + s];
        __syncthreads();
    }
    float sig = 1.f / (1.f + expf(-red[0]));

    int   s0 = slot[2*t],   s1 = slot[2*t+1];
    float w0 = wts[2*t],    w1 = wts[2*t+1];
    const __bf16* pr0 = pair_out + (size_t)s0 * NH;
    const __bf16* pr1 = pair_out + (size_t)s1 * NH;
    const __bf16* sd  = shp + (size_t)t * NH;
    float* orow = out + (size_t)t * NH;
    const size_t PS = (size_t)NT * NH;
    for (int n = tid; n < NH; n += 256) {
        float sdv = (float)sd[n] + (float)sd[n + PS];
        orow[n] = sdv * sig + w0 * (float)pr0[n] + w1 * (float)pr1[n];
    }
}

// ---------------- launch ----------------
extern "C" void kernel_launch(void* const* d_in, const int* in_sizes, int n_in,
                              void* d_out, int out_size, void* d_ws, size_t ws_size,
                              hipStream_t stream)
{
    const float* x       = (const float*)d_in[0];
    const float* gate_w  = (const float*)d_in[1];
    const float* w_gate  = (const float*)d_in[2];
    const float* w_up    = (const float*)d_in[3];
    const float* w_down  = (const float*)d_in[4];
    const float* sh_gate = (const float*)d_in[5];
    const float* sh_up   = (const float*)d_in[6];
    const float* sh_down = (const float*)d_in[7];
    const float* shexp_g = (const float*)d_in[8];

    float* out        = (float*)d_out;
    float* out_logits = out + (size_t)NT * NH;

    char* ws = (char*)d_ws;
    __bf16* xbf  = (__bf16*)(ws + WS_XBF);
    int*    sel  = (int*)  (ws + WS_SEL);
    float*  wts  = (float*)(ws + WS_WTS);
    int*    cnt  = (int*)  (ws + WS_CNT);
    int*    offe = (int*)  (ws + WS_OFFE);
    int*    tok  = (int*)  (ws + WS_TOK);
    float*  pwt  = (float*)(ws + WS_PWT);
    int*    slot = (int*)  (ws + WS_SLOT);
    __bf16* gbuf = (__bf16*)(ws + WS_G);
    __bf16* ubuf = (__bf16*)(ws + WS_U);
    __bf16* hbf  = (__bf16*)(ws + WS_HBF);
    __bf16* pair = (__bf16*)(ws + WS_PAIR);
    __bf16* shg  = (__bf16*)(ws + WS_SHG);
    __bf16* shu  = (__bf16*)(ws + WS_SHU);
    __bf16* shbf = (__bf16*)(ws + WS_SHBF);
    __bf16* shp  = (__bf16*)(ws + WS_SHP);
    (void)pwt; (void)in_sizes; (void)n_in; (void)out_size; (void)ws_size;

    router_kernel<<<dim3(128), dim3(256), 0, stream>>>(x, gate_w, out_logits, sel, wts);
    bucket_kernel<<<dim3(1), dim3(512), 0, stream>>>(sel, wts, cnt, offe, tok, pwt, slot);
    cast_kernel<<<dim3(1024), dim3(256), 0, stream>>>(x, xbf, (long long)NT * NH);

    // phase 1: XCD-local (8 XCDs x 112 slots)
    gemm_p1<<<dim3(896), dim3(256), 0, stream>>>(
        xbf, w_gate, w_up, sh_gate, sh_up, gbuf, ubuf, shg, shu, cnt, offe, tok);

    // silu
    silu_fused_kernel<<<dim3(2112), dim3(256), 0, stream>>>(
        gbuf, ubuf, hbf, (long long)1024 * NI,
        shg, shu, shbf, (long long)NT * NIS);

    // phase 3: XCD-local (8 XCDs x 72 slots)
    gemm_p3<<<dim3(576), dim3(256), 0, stream>>>(
        hbf, shbf, w_down, sh_down, pair, shp, cnt, offe);

    combine_kernel<<<dim3(NT), dim3(256), 0, stream>>>(
        x, shexp_g, shp, pair, slot, wts, out);
}

// Round 19
// 199.551 us; speedup vs baseline: 1.4309x; 1.4309x over previous
//
#include <hip/hip_runtime.h>
#include <hip/hip_bf16.h>

// ---------------- problem dims ----------------
#define NT  512      // tokens
#define NH  2048     // hidden
#define NE  8        // experts
#define NI  1408     // expert intermediate
#define NIS 5632     // shared intermediate

typedef __bf16 bf16x8 __attribute__((ext_vector_type(8)));
typedef float  f32x4  __attribute__((ext_vector_type(4)));

// async global->LDS DMA, 16B per lane, wave-uniform LDS base + lane*16
#define GLDS(gp, lp) __builtin_amdgcn_global_load_lds( \
    (const __attribute__((address_space(1))) void*)(gp), \
    (__attribute__((address_space(3))) void*)(lp), 16, 0, 0)

// ---------------- workspace layout (bytes) ----------------
static constexpr size_t WS_XBF  = 0;                                  // 512*2048 bf16
static constexpr size_t WS_SEL  = WS_XBF + (size_t)NT*NH*2;           // 1024 int
static constexpr size_t WS_WTS  = WS_SEL + 4096;
static constexpr size_t WS_CNT  = WS_WTS + 4096;
static constexpr size_t WS_OFFE = WS_CNT + 32;
static constexpr size_t WS_TOK  = WS_OFFE + 32;
static constexpr size_t WS_PWT  = WS_TOK + 4096;
static constexpr size_t WS_SLOT = WS_PWT + 4096;
static constexpr size_t WS_G    = WS_SLOT + 4096;                     // 1024*1408 bf16
static constexpr size_t WS_U    = WS_G   + (size_t)1024*NI*2;
static constexpr size_t WS_HBF  = WS_U   + (size_t)1024*NI*2;         // 1024*1408 bf16
static constexpr size_t WS_PAIR = WS_HBF + (size_t)1024*NI*2;         // 1024*2048 bf16
static constexpr size_t WS_SHG  = WS_PAIR+ (size_t)1024*NH*2;         // 512*5632 bf16
static constexpr size_t WS_SHU  = WS_SHG + (size_t)NT*NIS*2;
static constexpr size_t WS_SHBF = WS_SHU + (size_t)NT*NIS*2;          // 512*5632 bf16
static constexpr size_t WS_SHP  = WS_SHBF+ (size_t)NT*NIS*2;          // 4*512*2048 bf16

// ---------------- router: one wave per token ----------------
__global__ void router_kernel(const float* __restrict__ x, const float* __restrict__ gw,
                              float* __restrict__ out_logits,
                              int* __restrict__ sel, float* __restrict__ wts)
{
    int w    = threadIdx.x >> 6;
    int lane = threadIdx.x & 63;
    int t    = blockIdx.x * 4 + w;
    int e    = lane & 7, c = lane >> 3;
    const float* xr = x  + (size_t)t * NH + c * 256;
    const float* gr = gw + (size_t)e * NH + c * 256;
    float acc = 0.f;
    #pragma unroll 8
    for (int it = 0; it < 64; ++it) {
        float4 xv = *(const float4*)(xr + it*4);
        float4 gv = *(const float4*)(gr + it*4);
        acc += xv.x*gv.x + xv.y*gv.y + xv.z*gv.z + xv.w*gv.w;
    }
    acc += __shfl_xor(acc, 8);
    acc += __shfl_xor(acc, 16);
    acc += __shfl_xor(acc, 32);
    if (lane < 8) out_logits[(size_t)t * NE + e] = acc;

    float l[8];
    #pragma unroll
    for (int j = 0; j < 8; ++j) l[j] = __shfl(acc, j);
    if (lane == 0) {
        int i1 = 0;
        #pragma unroll
        for (int j = 1; j < 8; ++j) if (l[j] > l[i1]) i1 = j;
        int i2 = -1;
        #pragma unroll
        for (int j = 0; j < 8; ++j) {
            if (j == i1) continue;
            if (i2 < 0 || l[j] > l[i2]) i2 = j;
        }
        float d  = expf(l[i2] - l[i1]);
        float w1 = 1.f / (1.f + d);
        float w2 = 1.f - w1;
        sel[2*t]   = i1;  sel[2*t+1] = i2;
        wts[2*t]   = w1;  wts[2*t+1] = w2;
    }
}

// ---------------- wave-parallel deterministic bucketing ----------------
__global__ void bucket_kernel(const int* __restrict__ sel, const float* __restrict__ wts,
                              int* __restrict__ cnt, int* __restrict__ offe,
                              int* __restrict__ tok, float* __restrict__ pwt,
                              int* __restrict__ slot)
{
    int tid  = threadIdx.x;          // 0..511
    int wid  = tid >> 6;             // expert id
    int lane = tid & 63;
    __shared__ int scnt[8], soff[8];

    unsigned long long masks[16];
    int total = 0;
    #pragma unroll
    for (int c = 0; c < 16; ++c) {
        int idx = c * 64 + lane;
        int s = sel[idx];
        unsigned long long m = __ballot(s == wid);
        masks[c] = m;
        total += __popcll(m);
    }
    if (lane == 0) { scnt[wid] = total; cnt[wid] = total; }
    __syncthreads();
    if (tid == 0) {
        int s = 0;
        #pragma unroll
        for (int j = 0; j < 8; ++j) { soff[j] = s; offe[j] = s; s += scnt[j]; }
    }
    __syncthreads();
    int pfx = soff[wid];
    unsigned long long below = (lane == 63) ? ~0ull >> 1 : ((1ull << lane) - 1);
    #pragma unroll
    for (int c = 0; c < 16; ++c) {
        int idx = c * 64 + lane;
        unsigned long long m = masks[c];
        if ((m >> lane) & 1ull) {
            int rank = pfx + (int)__popcll(m & below);
            tok[rank]  = idx >> 1;
            pwt[rank]  = wts[idx];
            slot[idx]  = rank;
        }
        pfx += (int)__popcll(m);
    }
}

// ---------------- fp32 -> bf16 cast (activations) ----------------
__global__ void cast_kernel(const float* __restrict__ src, __bf16* __restrict__ dst, long long n)
{
    long long i = ((long long)blockIdx.x * blockDim.x + threadIdx.x) * 4;
    if (i >= n) return;
    float4 v = *(const float4*)(src + i);
    __bf16 o[4] = { (__bf16)v.x, (__bf16)v.y, (__bf16)v.z, (__bf16)v.w };
    *(uint2*)(dst + i) = *(const uint2*)o;
}

// ---------------- fused silu(g)*u (bf16 in/out) ----------------
__global__ void silu_fused_kernel(const __bf16* __restrict__ g1, const __bf16* __restrict__ u1,
                                  __bf16* __restrict__ h1, long long n1,
                                  const __bf16* __restrict__ g2, const __bf16* __restrict__ u2,
                                  __bf16* __restrict__ h2, long long n2)
{
    long long i = ((long long)blockIdx.x * blockDim.x + threadIdx.x) * 8;
    const __bf16 *g, *u; __bf16* h; long long idx;
    if (i < n1)           { g = g1; u = u1; h = h1; idx = i; }
    else if (i < n1 + n2) { g = g2; u = u2; h = h2; idx = i - n1; }
    else return;
    uint4 gv = *(const uint4*)(g + idx);
    uint4 uv = *(const uint4*)(u + idx);
    const __bf16* gp = (const __bf16*)&gv;
    const __bf16* up = (const __bf16*)&uv;
    __bf16 o[8];
    #pragma unroll
    for (int j = 0; j < 8; ++j) {
        float x = (float)gp[j];
        float y = x / (1.f + __expf(-x)) * (float)up[j];
        o[j] = (__bf16)y;
    }
    *(uint4*)(h + idx) = *(const uint4*)o;
}

// ============ core 128x128 MFMA GEMM — depth-2 pipeline ====================
// A bf16 [*, lda] via global_load_lds (XOR src swizzle), slot ring of 3.
// B fp32 [K, LDB] row-major: 16 coalesced dword loads/thread -> reg convert
//   -> 2x ds_write_b128 into swizzled bf16 [n][k] buffer (double-buffered).
// Statically unrolled by 2 (runtime-parity reg-array indexing spills!).
// Counted vmcnt(18); never 0 mid-loop.
// LDS: As[3][8192] @0 | Bbf[2][8192] @24576 = 40KB. NK even.
template<int NK, int LDB, bool GATHER>
__device__ __forceinline__ void gemm_core(char* __restrict__ smem,
    const __bf16* __restrict__ A, int lda,
    const float* __restrict__ B,
    __bf16* __restrict__ C, int ldc,
    int rows, int base, const int* __restrict__ tok, int m0, int n0)
{
    const int tid  = threadIdx.x;
    const int lane = tid & 63;
    const int wid  = tid >> 6;           // 4 waves, 2x2 grid of 64x64
    const int wr   = wid >> 1, wc = wid & 1;

    // ---- A staging (bf16 DMA): wave covers rows [wid*32, +32) in 2 instrs
    const int rs0 = (wid*2 + 0)*16 + (lane >> 2);
    const int rs1 = (wid*2 + 1)*16 + (lane >> 2);
    const int cch = lane & 3;
    int ga0 = m0 + rs0, ga1 = m0 + rs1;
    int ar0, ar1;
    if (GATHER) {
        ar0 = tok[base + (ga0 < rows ? ga0 : 0)];
        ar1 = tok[base + (ga1 < rows ? ga1 : 0)];
    } else {
        ar0 = base + (ga0 < rows ? ga0 : 0);
        ar1 = base + (ga1 < rows ? ga1 : 0);
    }
    const __bf16* a0p = A + (size_t)ar0 * lda + (cch ^ (rs0 & 3)) * 8;
    const __bf16* a1p = A + (size_t)ar1 * lda + (cch ^ (rs1 & 3)) * 8;

#define AGLDS(slot, t)                                               \
    {                                                                \
        char* d0 = smem + (slot)*8192 + (wid*2 + 0)*1024;            \
        char* d1 = smem + (slot)*8192 + (wid*2 + 1)*1024;            \
        GLDS(a0p + (size_t)(t)*32, d0);                              \
        GLDS(a1p + (size_t)(t)*32, d1);                              \
    }

    // ---- B: thread (cn, ckh) owns column n0+cn, k-half ckh (16 k values)
    const int cn  = tid & 127;
    const int ckh = tid >> 7;
    const int csw = (cn >> 1) & 3;               // bf16 chunk XOR swizzle
    const float* bp = B + (size_t)(ckh * 16) * LDB + n0 + cn;
    char* bbuf0 = smem + 24576;
    char* bbuf1 = smem + 32768;

#define BLOAD(R, t)                                                  \
    {                                                                \
        const float* bq = bp + (size_t)(t) * 32 * LDB;               \
        _Pragma("unroll")                                            \
        for (int j = 0; j < 16; ++j) R[j] = bq[(size_t)j * LDB];     \
    }

#define CONVERT(R, bbase)                                            \
    {                                                                \
        __bf16 ob[16];                                               \
        _Pragma("unroll")                                            \
        for (int j = 0; j < 16; ++j) ob[j] = (__bf16)R[j];           \
        *(uint4*)((bbase) + cn*64 + (((ckh*2 + 0) ^ csw) * 16)) = ((const uint4*)ob)[0]; \
        *(uint4*)((bbase) + cn*64 + (((ckh*2 + 1) ^ csw) * 16)) = ((const uint4*)ob)[1]; \
    }

    // ---- fragment read offsets (bytes)
    const int fr = lane & 15, fq = lane >> 4;
    const int aoff = (wr*64 + fr)*64 + ((fq ^ (fr & 3)) * 16);
    const int boff = (wc*64 + fr)*64 + ((fq ^ ((fr >> 1) & 3)) * 16);

    f32x4 acc[4][4];
    #pragma unroll
    for (int i = 0; i < 4; ++i)
        #pragma unroll
        for (int j = 0; j < 4; ++j) acc[i][j] = f32x4{0.f,0.f,0.f,0.f};

#define MFMAS(slot, bbase)                                           \
    {                                                                \
        const char* Ab = smem + (slot)*8192;                         \
        bf16x8 af[4], bfr[4];                                        \
        _Pragma("unroll")                                            \
        for (int m = 0; m < 4; ++m) af[m]  = *(const bf16x8*)(Ab + aoff + m*1024); \
        _Pragma("unroll")                                            \
        for (int n = 0; n < 4; ++n) bfr[n] = *(const bf16x8*)((bbase) + boff + n*1024); \
        __builtin_amdgcn_s_setprio(1);                               \
        _Pragma("unroll")                                            \
        for (int m = 0; m < 4; ++m)                                  \
            _Pragma("unroll")                                        \
            for (int n = 0; n < 4; ++n)                              \
                acc[m][n] = __builtin_amdgcn_mfma_f32_16x16x32_bf16(af[m], bfr[n], acc[m][n], 0, 0, 0); \
        __builtin_amdgcn_s_setprio(0);                               \
    }

    float b0[16], b1[16];

    // ---- prologue: stages 0,1 in flight; convert stage 0
    BLOAD(b0, 0); AGLDS(0, 0);
    BLOAD(b1, 1); AGLDS(1, 1);
    asm volatile("s_waitcnt vmcnt(18)" ::: "memory");   // stage 0 done
    CONVERT(b0, bbuf0);
    asm volatile("s_waitcnt lgkmcnt(0)" ::: "memory");
    __builtin_amdgcn_s_barrier();

    int sA = 0, sB = 1, sC = 2;                         // A slots for tiles t, t+1, t+2
    #pragma unroll 1
    for (int t = 0; t < NK; t += 2) {
        // ---- even tile t: A slot sA, B bbuf0
        if (t + 2 < NK) { BLOAD(b0, t + 2); AGLDS(sC, t + 2); }
        __builtin_amdgcn_sched_barrier(0);
        MFMAS(sA, bbuf0);
        __builtin_amdgcn_sched_barrier(0);
        if (t + 2 < NK) asm volatile("s_waitcnt vmcnt(18)" ::: "memory");  // stage t+1 done
        else            asm volatile("s_waitcnt vmcnt(0)" ::: "memory");
        CONVERT(b1, bbuf1);                              // stage t+1 -> bbuf1
        asm volatile("s_waitcnt lgkmcnt(0)" ::: "memory");
        __builtin_amdgcn_s_barrier();

        // ---- odd tile t+1: A slot sB, B bbuf1
        if (t + 3 < NK) { BLOAD(b1, t + 3); AGLDS(sA, t + 3); }
        __builtin_amdgcn_sched_barrier(0);
        MFMAS(sB, bbuf1);
        __builtin_amdgcn_sched_barrier(0);
        if (t + 2 < NK) {
            if (t + 3 < NK) asm volatile("s_waitcnt vmcnt(18)" ::: "memory");  // stage t+2 done
            else            asm volatile("s_waitcnt vmcnt(0)" ::: "memory");
            CONVERT(b0, bbuf0);                          // stage t+2 -> bbuf0
        }
        asm volatile("s_waitcnt lgkmcnt(0)" ::: "memory");
        __builtin_amdgcn_s_barrier();

        int tmp = sA; sA = sC; sC = sB; sB = tmp;
    }
#undef AGLDS
#undef BLOAD
#undef CONVERT
#undef MFMAS

    // ---- epilogue: per-wave LDS transpose (bf16), coalesced 16B row stores
    __bf16* ep = (__bf16*)(smem + wid * 9216);   // 64 rows x 72 bf16
    #pragma unroll
    for (int m = 0; m < 4; ++m)
        #pragma unroll
        for (int n = 0; n < 4; ++n)
            #pragma unroll
            for (int q = 0; q < 4; ++q)
                ep[(m*16 + fq*4 + q)*72 + n*16 + fr] = (__bf16)acc[m][n][q];

    const int grow = m0 + wr*64 + lane;
    if (grow < rows) {
        __bf16* cp = C + (size_t)(base + grow) * ldc + n0 + wc*64;
        const __bf16* rp = ep + lane * 72;
        #pragma unroll
        for (int j = 0; j < 8; ++j)
            *(uint4*)(cp + j*8) = *(const uint4*)(rp + j*8);
    }
}

// ---------------- phase 1, XCD-local 1-D mapping ---------------------------
// bid%8 = XCD. Per-XCD slots j in [0,136):
//   j < 88: expert x blocks. gu = j/44, r = j%44: n = r%11, m = r/11.
//   j >= 88: shared gate/up. s = j-88 in [0,48): z = s/24, rem = s%24,
//            i = rem/4 -> n = x+8i (guard n>=44), m = rem%4.
// Count: 704 expert + 352 shared = 1056 working blocks.
__launch_bounds__(256, 3)
__global__ void gemm_p1(const __bf16* __restrict__ xbf,
                        const float* __restrict__ w_gate, const float* __restrict__ w_up,
                        const float* __restrict__ sh_gate, const float* __restrict__ sh_up,
                        __bf16* __restrict__ gbuf, __bf16* __restrict__ ubuf,
                        __bf16* __restrict__ shg, __bf16* __restrict__ shu,
                        const int* __restrict__ cnt, const int* __restrict__ offe,
                        const int* __restrict__ tok)
{
    __shared__ alignas(16) char smem[40960];
    int g = blockIdx.x;
    int x = g & 7;            // XCD
    int j = g >> 3;           // per-XCD slot 0..135
    if (j < 88) {
        int gu = j / 44;
        int r  = j % 44;
        int n  = r % 11;
        int m  = r / 11;
        int rows = cnt[x], base = offe[x];
        int m0 = m * 128; if (m0 >= rows) return;
        const float* B = (gu == 0 ? w_gate : w_up) + (size_t)x * NH * NI;
        __bf16* C = (gu == 0 ? gbuf : ubuf);
        gemm_core<NH/32, NI, true>(smem, xbf, NH, B, C, NI,
                                   rows, base, tok, m0, n * 128);
    } else {
        int s = j - 88;           // 0..47
        int z = s / 24;
        int rem = s % 24;
        int i = rem >> 2;         // 0..5
        int m = rem & 3;          // 0..3
        int n = x + 8 * i;
        if (n >= 44) return;
        const float* B = (z == 0 ? sh_gate : sh_up);
        __bf16* C = (z == 0 ? shg : shu);
        gemm_core<NH/32, NIS, false>(smem, xbf, NH, B, C, NIS,
                                     NT, 0, nullptr, m * 128, n * 128);
    }
}

// ---------------- phase 3, XCD-local 1-D mapping ---------------------------
// XCD x: j<64 -> expert x down (16n x 4m; A panel XCD-local).
// j>=64 -> shared down split-K x4: s = j-64: q = s/8, i = (s%8)/4, m = s%4;
// n = x+8i; B quarter-panel's readers adjacent on one XCD.
__launch_bounds__(256, 3)
__global__ void gemm_p3(const __bf16* __restrict__ hbf, const __bf16* __restrict__ shbf,
                        const float* __restrict__ w_down, const float* __restrict__ sh_down,
                        __bf16* __restrict__ pair, __bf16* __restrict__ shp,
                        const int* __restrict__ cnt, const int* __restrict__ offe)
{
    __shared__ alignas(16) char smem[40960];
    int g = blockIdx.x;
    int x = g & 7;            // XCD
    int j = g >> 3;           // 0..95
    if (j < 64) {
        int n = j % 16;
        int m = j / 16;       // 0..3
        int rows = cnt[x], base = offe[x];
        int m0 = m * 128; if (m0 >= rows) return;
        gemm_core<NI/32, NH, false>(smem, hbf, NI, w_down + (size_t)x * NI * NH,
                                    pair, NH, rows, base, nullptr, m0, n * 128);
    } else {
        int s = j - 64;       // 0..31
        int q = s >> 3;       // K-quarter 0..3
        int rem = s & 7;
        int i = rem >> 2;
        int m = rem & 3;
        int n = x + 8 * i;    // 0..15
        gemm_core<NI/32, NH, false>(smem, shbf + q * NI, NIS,
                                    sh_down + (size_t)q * NI * NH,
                                    shp + (size_t)q * NT * NH, NH,
                                    NT, 0, nullptr, m * 128, n * 128);
    }
}

// ---------------- final combine ----------------
__global__ void combine_kernel(const float* __restrict__ x, const float* __restrict__ shexp_w,
                               const __bf16* __restrict__ shp, const __bf16* __restrict__ pair_out,
                               const int* __restrict__ slot, const float* __restrict__ wts,
                               float* __restrict__ out)
{
    int t = blockIdx.x;
    int tid = threadIdx.x;
    const float* xr = x + (size_t)t * NH;

    float p = 0.f;
    #pragma unroll
    for (int j = 0; j < 8; ++j) {
        int k = tid * 8 + j;
        p += xr[k] * shexp_w[k];
    }
    __shared__ float red[256];
    red[tid] = p;
    __syncthreads();
    for (int s = 128; s > 0; s >>= 1) {
        if (tid < s) red[tid] += red[tid + s];
        __syncthreads();
    }
    float sig = 1.f / (1.f + expf(-red[0]));

    int   s0 = slot[2*t],   s1 = slot[2*t+1];
    float w0 = wts[2*t],    w1 = wts[2*t+1];
    const __bf16* pr0 = pair_out + (size_t)s0 * NH;
    const __bf16* pr1 = pair_out + (size_t)s1 * NH;
    const __bf16* sd  = shp + (size_t)t * NH;
    float* orow = out + (size_t)t * NH;
    const size_t PS = (size_t)NT * NH;
    for (int n = tid; n < NH; n += 256) {
        float sdv = (float)sd[n] + (float)sd[n + PS] + (float)sd[n + 2*PS] + (float)sd[n + 3*PS];
        orow[n] = sdv * sig + w0 * (float)pr0[n] + w1 * (float)pr1[n];
    }
}

// ---------------- launch ----------------
extern "C" void kernel_launch(void* const* d_in, const int* in_sizes, int n_in,
                              void* d_out, int out_size, void* d_ws, size_t ws_size,
                              hipStream_t stream)
{
    const float* x       = (const float*)d_in[0];
    const float* gate_w  = (const float*)d_in[1];
    const float* w_gate  = (const float*)d_in[2];
    const float* w_up    = (const float*)d_in[3];
    const float* w_down  = (const float*)d_in[4];
    const float* sh_gate = (const float*)d_in[5];
    const float* sh_up   = (const float*)d_in[6];
    const float* sh_down = (const float*)d_in[7];
    const float* shexp_g = (const float*)d_in[8];

    float* out        = (float*)d_out;
    float* out_logits = out + (size_t)NT * NH;

    char* ws = (char*)d_ws;
    __bf16* xbf  = (__bf16*)(ws + WS_XBF);
    int*    sel  = (int*)  (ws + WS_SEL);
    float*  wts  = (float*)(ws + WS_WTS);
    int*    cnt  = (int*)  (ws + WS_CNT);
    int*    offe = (int*)  (ws + WS_OFFE);
    int*    tok  = (int*)  (ws + WS_TOK);
    float*  pwt  = (float*)(ws + WS_PWT);
    int*    slot = (int*)  (ws + WS_SLOT);
    __bf16* gbuf = (__bf16*)(ws + WS_G);
    __bf16* ubuf = (__bf16*)(ws + WS_U);
    __bf16* hbf  = (__bf16*)(ws + WS_HBF);
    __bf16* pair = (__bf16*)(ws + WS_PAIR);
    __bf16* shg  = (__bf16*)(ws + WS_SHG);
    __bf16* shu  = (__bf16*)(ws + WS_SHU);
    __bf16* shbf = (__bf16*)(ws + WS_SHBF);
    __bf16* shp  = (__bf16*)(ws + WS_SHP);
    (void)pwt; (void)in_sizes; (void)n_in; (void)out_size; (void)ws_size;

    router_kernel<<<dim3(128), dim3(256), 0, stream>>>(x, gate_w, out_logits, sel, wts);
    bucket_kernel<<<dim3(1), dim3(512), 0, stream>>>(sel, wts, cnt, offe, tok, pwt, slot);
    cast_kernel<<<dim3(1024), dim3(256), 0, stream>>>(x, xbf, (long long)NT * NH);

    // phase 1: XCD-local 1-D grid (8 XCDs x 136 slots)
    gemm_p1<<<dim3(1088), dim3(256), 0, stream>>>(
        xbf, w_gate, w_up, sh_gate, sh_up, gbuf, ubuf, shg, shu, cnt, offe, tok);

    // silu
    silu_fused_kernel<<<dim3(2112), dim3(256), 0, stream>>>(
        gbuf, ubuf, hbf, (long long)1024 * NI,
        shg, shu, shbf, (long long)NT * NIS);

    // phase 3: XCD-local 1-D grid (8 XCDs x 96 slots)
    gemm_p3<<<dim3(768), dim3(256), 0, stream>>>(
        hbf, shbf, w_down, sh_down, pair, shp, cnt, offe);

    combine_kernel<<<dim3(NT), dim3(256), 0, stream>>>(
        x, shexp_g, shp, pair, slot, wts, out);
}